// Round 5
// baseline (34367.896 us; speedup 1.0000x reference)
//
#include <hip/hip_runtime.h>
#include <stdint.h>

#define TT 512
#define BB 64
#define MM (BB * TT)  // 32768

typedef short bf16x8 __attribute__((ext_vector_type(8)));
typedef float f32x4  __attribute__((ext_vector_type(4)));

#define LNP ((size_t)MM * 1024)  // plane stride for g_ln (elements)

// ---- static device workspace ----
__device__ __align__(256) float g_xg[(size_t)MM * 3072];       // 384 MB fp32 input projections
__device__ __align__(256) unsigned short g_hex[176160768];     // 352 MB per-layer h, hi+lo planes
__device__ __align__(256) unsigned short g_ln[2 * LNP];        // 128 MB layer input, hi+lo bf16
__device__ __align__(256) unsigned short g_w[18579456];        // 37 MB weights hi+lo bf16
__device__ unsigned g_cnt[6 * TT * 8 * 16];                    // grouped step counters (64B apart)

__device__ __forceinline__ float bf2f(unsigned short u) {
  union { unsigned int i; float f; } c; c.i = ((unsigned int)u) << 16; return c.f;
}
__device__ __forceinline__ unsigned short f2bf(float f) {
  union { float f; unsigned int i; } c; c.f = f;
  unsigned int u = c.i;
  return (unsigned short)((u + 0x7FFFu + ((u >> 16) & 1u)) >> 16);
}

__device__ __forceinline__ void gload16(const void* g, void* l) {
  __builtin_amdgcn_global_load_lds(
      (const __attribute__((address_space(1))) unsigned int*)g,
      (__attribute__((address_space(3))) unsigned int*)l, 16, 0, 0);
}

// ---------------- zero the counters ----------------
__global__ void __launch_bounds__(256) k_zero() {
  int i = blockIdx.x * 256 + threadIdx.x;
  int st = gridDim.x * 256;
  for (; i < 6 * TT * 8 * 16; i += st) g_cnt[i] = 0;
}

// ---------------- f32 -> split bf16 (hi+lo) converts ----------------
__global__ void __launch_bounds__(256) k_cvt_split(const float* __restrict__ s, int n,
                                                   int offh, int offl) {
  int i = blockIdx.x * 256 + threadIdx.x;
  int st = gridDim.x * 256;
  for (; i < n; i += st) {
    float v = s[i];
    unsigned short hi = f2bf(v);
    g_w[offh + i] = hi;
    g_w[offl + i] = f2bf(v - bf2f(hi));
  }
}
__global__ void __launch_bounds__(256) k_cvt_x(const float* __restrict__ s, int n) {
  int i = blockIdx.x * 256 + threadIdx.x;
  int st = gridDim.x * 256;
  for (; i < n; i += st) {
    float v = s[i];
    unsigned short hi = f2bf(v);
    g_ln[i] = hi;
    g_ln[LNP + i] = f2bf(v - bf2f(hi));
  }
}

// ---------------- split-bf16 GEMM  C[M][N] = A[M][K] * B[N][K]^T ----------------
// acc += Ah*Bh + Al*Bh + Ah*Bl   (Al*Bl ~2^-18, dropped)
__global__ void __launch_bounds__(256) k_gemm(int N, int K, int bhoff, int bloff) {
  __shared__ char sm[65536];
  char* Ah = sm;
  char* Al = sm + 16384;
  char* Bh = sm + 32768;
  char* Bl = sm + 49152;
  const unsigned short* A0 = g_ln;
  const unsigned short* A1 = g_ln + LNP;
  const unsigned short* B0 = g_w + bhoff;
  const unsigned short* B1 = g_w + bloff;
  const int tid = threadIdx.x;
  const int lane = tid & 63;
  const int w = tid >> 6;
  const int wm = w >> 1, wn = w & 1;
  const int m0 = blockIdx.x * 128, n0 = blockIdx.y * 128;
  const int c16 = lane & 15, r4 = lane >> 4;

  f32x4 acc[4][4];
#pragma unroll
  for (int i = 0; i < 4; ++i)
#pragma unroll
    for (int j = 0; j < 4; ++j) acc[i][j] = {0.f, 0.f, 0.f, 0.f};

  for (int k0 = 0; k0 < K; k0 += 64) {
    __syncthreads();
#pragma unroll
    for (int i = 0; i < 4; ++i) {
      int c = i * 256 + tid;
      int row = c >> 3, ch = c & 7;
      size_t ao = (size_t)(m0 + row) * K + k0 + ch * 8;
      size_t bo = (size_t)(n0 + row) * K + k0 + ch * 8;
      gload16(A0 + ao, Ah + c * 16);
      gload16(A1 + ao, Al + c * 16);
      gload16(B0 + bo, Bh + c * 16);
      gload16(B1 + bo, Bl + c * 16);
    }
    __syncthreads();
#pragma unroll
    for (int ks = 0; ks < 2; ++ks) {
      bf16x8 avh[4], avl[4], bvh[4], bvl[4];
#pragma unroll
      for (int mt = 0; mt < 4; ++mt) {
        int o = (wm * 64 + mt * 16 + c16) * 128 + ks * 64 + r4 * 16;
        avh[mt] = *(const bf16x8*)(Ah + o);
        avl[mt] = *(const bf16x8*)(Al + o);
      }
#pragma unroll
      for (int nt = 0; nt < 4; ++nt) {
        int o = (wn * 64 + nt * 16 + c16) * 128 + ks * 64 + r4 * 16;
        bvh[nt] = *(const bf16x8*)(Bh + o);
        bvl[nt] = *(const bf16x8*)(Bl + o);
      }
#pragma unroll
      for (int mt = 0; mt < 4; ++mt)
#pragma unroll
        for (int nt = 0; nt < 4; ++nt) {
          acc[mt][nt] = __builtin_amdgcn_mfma_f32_16x16x32_bf16(avh[mt], bvh[nt], acc[mt][nt], 0, 0, 0);
          acc[mt][nt] = __builtin_amdgcn_mfma_f32_16x16x32_bf16(avl[mt], bvh[nt], acc[mt][nt], 0, 0, 0);
          acc[mt][nt] = __builtin_amdgcn_mfma_f32_16x16x32_bf16(avh[mt], bvl[nt], acc[mt][nt], 0, 0, 0);
        }
    }
  }
#pragma unroll
  for (int mt = 0; mt < 4; ++mt)
#pragma unroll
    for (int nt = 0; nt < 4; ++nt) {
      int col = n0 + wn * 64 + nt * 16 + c16;
#pragma unroll
      for (int q = 0; q < 4; ++q) {
        int row = m0 + wm * 64 + mt * 16 + r4 * 4 + q;
        g_xg[(size_t)row * N + col] = acc[mt][nt][q];
      }
    }
}

// ---------------- GRU scan, split h x split Whh ----------------
// Block owns h-cols [bid*NCOL, ...). Whh hi+lo in LDS (<=48KB), XOR-swizzled.
// Per-layer hex region (hoff): [hi plane T*B*H][lo plane T*B*H] -> cross-replay
// stale reads are benign (identical values). Sync: grouped counters, relaxed
// poll + one acquire fence; release atomicAdd per block per step.
template <int H, int NCOL, int NBLK, int NG>
__global__ void __launch_bounds__(256) k_scan(int whoff, int wloff,
                                              unsigned long long hoff, int coff) {
  constexpr int RB = 2 * H;
  constexpr int KI = H / 32;
  constexpr int ROWS = 3 * NCOL;
  constexpr int PL = ROWS * RB;
  constexpr unsigned TGT = NBLK / NG;
  __shared__ char lds[2 * PL];
  unsigned short* hexh = g_hex + hoff;                       // hi plane
  unsigned short* hexl = hexh + (size_t)TT * BB * H;         // lo plane
  const int tid = threadIdx.x;
  const int lane = tid & 63;
  const int w = tid >> 6;
  const int bid = blockIdx.x;
  const int jb = bid * NCOL;
  const int c16 = lane & 15, r4 = lane >> 4;

  {  // prologue: Whh rows {p*H + jb + j} -> LDS row p*NCOL+j (both planes), swizzled by row
    constexpr int CPR = RB / 16;
    const unsigned short* wh = g_w + whoff;
    const unsigned short* wl = g_w + wloff;
    for (int c = tid; c < ROWS * CPR; c += 256) {
      int r = c / CPR, ch = c % CPR;
      int p = r / NCOL, j = r % NCOL;
      size_t so = (size_t)(p * H + jb + j) * H + ch * 8;
      int byte = (ch * 16) ^ ((r & 7) << 4);
      *(float4*)(lds + r * RB + byte) = *(const float4*)(wh + so);
      *(float4*)(lds + PL + r * RB + byte) = *(const float4*)(wl + so);
    }
  }
  __syncthreads();

  float hprev[4] = {0.f, 0.f, 0.f, 0.f};
  const int rA = c16 & (NCOL - 1);
  const int grp = bid & (NG - 1);

  for (int t = 0; t < TT; ++t) {
    // prefetch xg[t] (no dependence on the t-1 sync)
    float xr[4], xz[4], xn[4];
    if (NCOL == 16 || c16 < NCOL) {
#pragma unroll
      for (int q = 0; q < 4; ++q) {
        int b = w * 16 + r4 * 4 + q;
        size_t xo = ((size_t)b * TT + t) * (3 * H) + jb + c16;
        xr[q] = g_xg[xo];
        xz[q] = g_xg[xo + H];
        xn[q] = g_xg[xo + 2 * H];
      }
    } else {
#pragma unroll
      for (int q = 0; q < 4; ++q) { xr[q] = 0.f; xz[q] = 0.f; xn[q] = 0.f; }
    }

    f32x4 acc[3];
#pragma unroll
    for (int g = 0; g < 3; ++g) acc[g] = {0.f, 0.f, 0.f, 0.f};

    if (t > 0) {
      if (tid < 64) {
        const unsigned* cp = g_cnt + ((size_t)(coff + t - 1) * 8) * 16;
        for (;;) {
          unsigned v = (lane < NG)
              ? __hip_atomic_load(cp + lane * 16, __ATOMIC_RELAXED, __HIP_MEMORY_SCOPE_AGENT)
              : TGT;
          if (__all(v >= TGT)) break;
        }
      }
      __builtin_amdgcn_fence(__ATOMIC_ACQUIRE, "agent");
      __syncthreads();

      const unsigned short* hrh = hexh + ((size_t)(t - 1) * BB + (w * 16 + c16)) * H + r4 * 8;
      const unsigned short* hrl = hexl + ((size_t)(t - 1) * BB + (w * 16 + c16)) * H + r4 * 8;
#pragma unroll 4
      for (int ki = 0; ki < KI; ++ki) {
        bf16x8 ah = *(const bf16x8*)(hrh + ki * 32);
        bf16x8 al = *(const bf16x8*)(hrl + ki * 32);
#pragma unroll
        for (int g = 0; g < 3; ++g) {
          const int row = g * NCOL + rA;
          const int ko = (ki * 64 + r4 * 16) ^ ((row & 7) << 4);
          const char* bp = lds + row * RB + ko;
          bf16x8 bh = *(const bf16x8*)bp;
          bf16x8 bl = *(const bf16x8*)(bp + PL);
          acc[g] = __builtin_amdgcn_mfma_f32_16x16x32_bf16(ah, bh, acc[g], 0, 0, 0);
          acc[g] = __builtin_amdgcn_mfma_f32_16x16x32_bf16(al, bh, acc[g], 0, 0, 0);
          acc[g] = __builtin_amdgcn_mfma_f32_16x16x32_bf16(ah, bl, acc[g], 0, 0, 0);
        }
      }
    }

    if (NCOL == 16 || c16 < NCOL) {
#pragma unroll
      for (int q = 0; q < 4; ++q) {
        int b = w * 16 + r4 * 4 + q;
        float rg = 1.f / (1.f + __expf(-(xr[q] + acc[0][q])));
        float zg = 1.f / (1.f + __expf(-(xz[q] + acc[1][q])));
        float ng = tanhf(xn[q] + rg * acc[2][q]);
        float h = (1.f - zg) * ng + zg * hprev[q];
        hprev[q] = h;
        size_t ho = ((size_t)t * BB + b) * H + jb + c16;
        unsigned short hi = f2bf(h);
        __builtin_nontemporal_store(hi, &hexh[ho]);
        __builtin_nontemporal_store(f2bf(h - bf2f(hi)), &hexl[ho]);
      }
    }
    __syncthreads();
    if (tid == 0)
      (void)__hip_atomic_fetch_add(g_cnt + ((size_t)(coff + t) * 8 + grp) * 16, 1u,
                                   __ATOMIC_RELEASE, __HIP_MEMORY_SCOPE_AGENT);
  }
}

// ---------------- LayerNorm (eps=0): reads per-layer hex hi+lo, row r = b*T+t ----------------
template <int H, bool LAST>
__global__ void __launch_bounds__(256) k_ln(const float* __restrict__ gw,
                                            const float* __restrict__ bw,
                                            float* __restrict__ of32,
                                            unsigned long long hoff) {
  const int r = blockIdx.x * 4 + (threadIdx.x >> 6);
  const int lane = threadIdx.x & 63;
  const int b = r >> 9;
  const int t = r & 511;
  const unsigned short* row = g_hex + hoff + ((size_t)t * BB + b) * H;
  const unsigned short* rowl = row + (size_t)TT * BB * H;
  constexpr int E = H / 64;
  float x[E];
  if constexpr (E == 16) {
#pragma unroll
    for (int jj = 0; jj < 2; ++jj) {
      bf16x8 v = *(const bf16x8*)(row + (lane + jj * 64) * 8);
      bf16x8 u = *(const bf16x8*)(rowl + (lane + jj * 64) * 8);
#pragma unroll
      for (int e = 0; e < 8; ++e) x[jj * 8 + e] = bf2f((unsigned short)v[e]) + bf2f((unsigned short)u[e]);
    }
  } else if constexpr (E == 8) {
    bf16x8 v = *(const bf16x8*)(row + lane * 8);
    bf16x8 u = *(const bf16x8*)(rowl + lane * 8);
#pragma unroll
    for (int e = 0; e < 8; ++e) x[e] = bf2f((unsigned short)v[e]) + bf2f((unsigned short)u[e]);
  } else if constexpr (E == 4) {
    typedef short bf16x4 __attribute__((ext_vector_type(4)));
    bf16x4 v = *(const bf16x4*)(row + lane * 4);
    bf16x4 u = *(const bf16x4*)(rowl + lane * 4);
#pragma unroll
    for (int e = 0; e < 4; ++e) x[e] = bf2f((unsigned short)v[e]) + bf2f((unsigned short)u[e]);
  } else {
    typedef short bf16x2 __attribute__((ext_vector_type(2)));
    bf16x2 v = *(const bf16x2*)(row + lane * 2);
    bf16x2 u = *(const bf16x2*)(rowl + lane * 2);
#pragma unroll
    for (int e = 0; e < 2; ++e) x[e] = bf2f((unsigned short)v[e]) + bf2f((unsigned short)u[e]);
  }
  float s = 0.f;
#pragma unroll
  for (int e = 0; e < E; ++e) s += x[e];
#pragma unroll
  for (int m = 1; m < 64; m <<= 1) s += __shfl_xor(s, m);
  const float mean = s * (1.f / H);
  float vs = 0.f;
#pragma unroll
  for (int e = 0; e < E; ++e) { float d = x[e] - mean; vs += d * d; }
#pragma unroll
  for (int m = 1; m < 64; m <<= 1) vs += __shfl_xor(vs, m);
  const float rstd = rsqrtf(vs * (1.f / H));
#pragma unroll
  for (int e = 0; e < E; ++e) {
    int col;
    if constexpr (E == 16) col = (lane + (e >> 3) * 64) * 8 + (e & 7);
    else col = lane * E + e;
    float y = (x[e] - mean) * rstd * gw[col] + bw[col];
    if constexpr (LAST) {
      of32[(size_t)r * H + col] = y;
    } else {
      unsigned short hi = f2bf(y);
      g_ln[(size_t)r * H + col] = hi;
      g_ln[LNP + (size_t)r * H + col] = f2bf(y - bf2f(hi));
    }
  }
}

extern "C" void kernel_launch(void* const* d_in, const int* in_sizes, int n_in,
                              void* d_out, int out_size, void* d_ws, size_t ws_size,
                              hipStream_t stream) {
  (void)in_sizes; (void)n_in; (void)out_size; (void)d_ws; (void)ws_size;
  static const int DIN[6] = {128, 256, 512, 1024, 512, 256};
  static const int HS[6]  = {256, 512, 1024, 512, 256, 128};
  const int M = MM;

  // packed weight offsets (elements)
  int wihh_off[6], wihl_off[6], whhh_off[6], whhl_off[6];
  unsigned long long hex_off[6];
  {
    int off = 0;
    unsigned long long hoff = 0;
    for (int l = 0; l < 6; ++l) {
      int sih = 3 * HS[l] * DIN[l], shh = 3 * HS[l] * HS[l];
      wihh_off[l] = off; off += sih;
      wihl_off[l] = off; off += sih;
      whhh_off[l] = off; off += shh;
      whhl_off[l] = off; off += shh;
      hex_off[l] = hoff; hoff += 2ull * TT * BB * HS[l];
    }
  }

  k_zero<<<384, 256, 0, stream>>>();
  k_cvt_x<<<1024, 256, 0, stream>>>((const float*)d_in[0], M * 128);
  for (int l = 0; l < 6; ++l) {
    k_cvt_split<<<512, 256, 0, stream>>>((const float*)d_in[1 + 4 * l], 3 * HS[l] * DIN[l],
                                         wihh_off[l], wihl_off[l]);
    k_cvt_split<<<512, 256, 0, stream>>>((const float*)d_in[2 + 4 * l], 3 * HS[l] * HS[l],
                                         whhh_off[l], whhl_off[l]);
  }

  for (int l = 0; l < 6; ++l) {
    const int H = HS[l], K = DIN[l], N = 3 * H;
    dim3 gg(M / 128, N / 128);
    k_gemm<<<gg, 256, 0, stream>>>(N, K, wihh_off[l], wihl_off[l]);

    const int coff = l * TT;
    switch (H) {
      case 1024: k_scan<1024, 4, 256, 8><<<256, 256, 0, stream>>>(whhh_off[l], whhl_off[l], hex_off[l], coff); break;
      case 512:  k_scan<512, 8, 64, 4><<<64, 256, 0, stream>>>(whhh_off[l], whhl_off[l], hex_off[l], coff); break;
      case 256:  k_scan<256, 16, 16, 2><<<16, 256, 0, stream>>>(whhh_off[l], whhl_off[l], hex_off[l], coff); break;
      case 128:  k_scan<128, 16, 8, 2><<<8, 256, 0, stream>>>(whhh_off[l], whhl_off[l], hex_off[l], coff); break;
    }

    const float* gp = (const float*)d_in[3 + 4 * l];
    const float* bp = (const float*)d_in[4 + 4 * l];
    if (l == 5) {
      k_ln<128, true><<<M / 4, 256, 0, stream>>>(gp, bp, (float*)d_out, hex_off[l]);
    } else {
      switch (H) {
        case 1024: k_ln<1024, false><<<M / 4, 256, 0, stream>>>(gp, bp, nullptr, hex_off[l]); break;
        case 512:  k_ln<512, false><<<M / 4, 256, 0, stream>>>(gp, bp, nullptr, hex_off[l]); break;
        case 256:  k_ln<256, false><<<M / 4, 256, 0, stream>>>(gp, bp, nullptr, hex_off[l]); break;
      }
    }
  }
}